// Round 1
// baseline (650.472 us; speedup 1.0000x reference)
//
#include <hip/hip_runtime.h>
#include <hip/hip_bf16.h>
#include <math.h>

#define N_NODES 100000
#define N_EDGES 1600000
#define IN_DIM 256
#define OUT_DIM 64

// ---------------------------------------------------------------------------
// Kernel A: W_h = h @ W.T  (100000x256 @ 256x64), plus per-node scalars
//   p_src[i] = W_h[i,:] . a[:64],  p_dst[i] = W_h[i,:] . a[64:]
// Layout: 256 thr = 4 waves; each wave owns 8 nodes per iteration.
// Lane c computes output column c. W staged in LDS as Wt4[k4][c] (float4 of
// W[c][4k4..4k4+3]); h rows read via wave-uniform pointer -> s_load + v_fma.
// ---------------------------------------------------------------------------
__global__ __launch_bounds__(256, 2) void gat_gemm(
    const float* __restrict__ h, const float* __restrict__ W,
    const float* __restrict__ a, float* __restrict__ Wh,
    float* __restrict__ p_src, float* __restrict__ p_dst)
{
    __shared__ float4 Wt4[64 * 64];   // 64 KiB: Wt4[k4*64 + c] = W[c][4k4..+3]
    const int t = threadIdx.x;
    for (int idx = t; idx < 64 * 64; idx += 256) {
        const int c = idx >> 6, k4 = idx & 63;
        Wt4[k4 * 64 + c] = *reinterpret_cast<const float4*>(W + c * IN_DIM + k4 * 4);
    }
    __syncthreads();

    const int lane = t & 63;
    const float a_s = a[lane];
    const float a_d = a[OUT_DIM + lane];

    const int n_gwaves = gridDim.x * 4;
    const int gwave = blockIdx.x * 4 + (t >> 6);

    for (int base = gwave * 8; base < N_NODES; base += n_gwaves * 8) {
        // base is wave-uniform; force SGPR so h reads become scalar loads
        const int ub = __builtin_amdgcn_readfirstlane(base);
        const float* __restrict__ hrow = h + (size_t)ub * IN_DIM;

        float acc[8];
        #pragma unroll
        for (int n = 0; n < 8; ++n) acc[n] = 0.f;

        for (int k4 = 0; k4 < 64; ++k4) {
            const float4 w = Wt4[k4 * 64 + lane];
            #pragma unroll
            for (int n = 0; n < 8; ++n) {
                acc[n] = fmaf(hrow[n * IN_DIM + k4 * 4 + 0], w.x, acc[n]);
                acc[n] = fmaf(hrow[n * IN_DIM + k4 * 4 + 1], w.y, acc[n]);
                acc[n] = fmaf(hrow[n * IN_DIM + k4 * 4 + 2], w.z, acc[n]);
                acc[n] = fmaf(hrow[n * IN_DIM + k4 * 4 + 3], w.w, acc[n]);
            }
        }

        #pragma unroll
        for (int n = 0; n < 8; ++n) {
            Wh[(size_t)(base + n) * OUT_DIM + lane] = acc[n];
            float ps = acc[n] * a_s;
            float pd = acc[n] * a_d;
            #pragma unroll
            for (int off = 32; off > 0; off >>= 1) {
                ps += __shfl_xor(ps, off);
                pd += __shfl_xor(pd, off);
            }
            if (lane == 0) {
                p_src[base + n] = ps;
                p_dst[base + n] = pd;
            }
        }
    }
}

// ---------------------------------------------------------------------------
// Kernel B: per-edge e = relu(p_src[src] + p_dst[dst]); m[dst] = max(e).
// e >= 0, so float-max == uint-max on the bit pattern with 0-init.
// ---------------------------------------------------------------------------
__global__ __launch_bounds__(256) void gat_edge_max(
    const int* __restrict__ src, const int* __restrict__ dst,
    const float* __restrict__ p_src, const float* __restrict__ p_dst,
    unsigned int* __restrict__ m_bits)
{
    const int e = blockIdx.x * 256 + threadIdx.x;
    if (e >= N_EDGES) return;
    const int se = src[e], de = dst[e];
    const float val = fmaxf(p_src[se] + p_dst[de], 0.f);
    atomicMax(m_bits + de, __float_as_uint(val));
}

// ---------------------------------------------------------------------------
// Kernel C: s[dst] += exp(e - m[dst])  (e recomputed; deterministic inputs)
// ---------------------------------------------------------------------------
__global__ __launch_bounds__(256) void gat_edge_sum(
    const int* __restrict__ src, const int* __restrict__ dst,
    const float* __restrict__ p_src, const float* __restrict__ p_dst,
    const float* __restrict__ m, float* __restrict__ s)
{
    const int e = blockIdx.x * 256 + threadIdx.x;
    if (e >= N_EDGES) return;
    const int se = src[e], de = dst[e];
    const float val = fmaxf(p_src[se] + p_dst[de], 0.f);
    const float ex = __expf(val - m[de]);
    atomicAdd(s + de, ex);
}

// ---------------------------------------------------------------------------
// Kernel D: h_N[dst] += alpha * W_h[src].  One wave per edge, lane = column.
// alpha recomputed per edge (broadcast loads, all lanes same address).
// ---------------------------------------------------------------------------
__global__ __launch_bounds__(256) void gat_aggregate(
    const int* __restrict__ src, const int* __restrict__ dst,
    const float* __restrict__ p_src, const float* __restrict__ p_dst,
    const float* __restrict__ m, const float* __restrict__ s,
    const float* __restrict__ Wh, float* __restrict__ out)
{
    const int lane = threadIdx.x & 63;
    const int gwave = (blockIdx.x * 256 + threadIdx.x) >> 6;
    if (gwave >= N_EDGES) return;
    const int se = src[gwave], de = dst[gwave];
    const float val = fmaxf(p_src[se] + p_dst[de], 0.f);
    const float alpha = __expf(val - m[de]) / s[de];
    const float w = Wh[(size_t)se * OUT_DIM + lane];
    atomicAdd(out + (size_t)de * OUT_DIM + lane, alpha * w);
}

// ---------------------------------------------------------------------------
extern "C" void kernel_launch(void* const* d_in, const int* in_sizes, int n_in,
                              void* d_out, int out_size, void* d_ws, size_t ws_size,
                              hipStream_t stream)
{
    const float* h  = (const float*)d_in[0];
    const int* src  = (const int*)d_in[1];
    const int* dst  = (const int*)d_in[2];
    const float* W  = (const float*)d_in[3];
    const float* a  = (const float*)d_in[4];
    float* out = (float*)d_out;

    // workspace layout (bytes): Wh 25.6e6 | p_src 0.4e6 | p_dst 0.4e6 | m 0.4e6 | s 0.4e6
    char* ws = (char*)d_ws;
    float* Wh    = (float*)(ws);
    float* p_src = (float*)(ws + 25600000);
    float* p_dst = (float*)(ws + 26000000);
    float* m     = (float*)(ws + 26400000);
    float* s     = (float*)(ws + 26800000);

    hipMemsetAsync(m, 0, N_NODES * sizeof(float), stream);
    hipMemsetAsync(s, 0, N_NODES * sizeof(float), stream);
    hipMemsetAsync(out, 0, (size_t)out_size * sizeof(float), stream);

    gat_gemm<<<512, 256, 0, stream>>>(h, W, a, Wh, p_src, p_dst);

    const int eb = (N_EDGES + 255) / 256;
    gat_edge_max<<<eb, 256, 0, stream>>>(src, dst, p_src, p_dst, (unsigned int*)m);
    gat_edge_sum<<<eb, 256, 0, stream>>>(src, dst, p_src, p_dst, m, s);

    // one wave per edge: N_EDGES/4 blocks of 4 waves
    gat_aggregate<<<N_EDGES / 4, 256, 0, stream>>>(src, dst, p_src, p_dst, m, s, Wh, out);
}

// Round 2
// 362.271 us; speedup vs baseline: 1.7955x; 1.7955x over previous
//
#include <hip/hip_runtime.h>
#include <hip/hip_bf16.h>
#include <math.h>

#define N_NODES 100000
#define N_EDGES 1600000
#define IN_DIM 256
#define OUT_DIM 64

// ---------------------------------------------------------------------------
// Kernel A: W_h = h @ W.T  (100000x256 @ 256x64), plus per-node scalars
//   p_src[i] = W_h[i,:] . a[:64],  p_dst[i] = W_h[i,:] . a[64:]
// (unchanged from round 1 — isolate the aggregation fix; profile this next)
// ---------------------------------------------------------------------------
__global__ __launch_bounds__(256, 2) void gat_gemm(
    const float* __restrict__ h, const float* __restrict__ W,
    const float* __restrict__ a, float* __restrict__ Wh,
    float* __restrict__ p_src, float* __restrict__ p_dst)
{
    __shared__ float4 Wt4[64 * 64];   // 64 KiB: Wt4[k4*64 + c] = W[c][4k4..+3]
    const int t = threadIdx.x;
    for (int idx = t; idx < 64 * 64; idx += 256) {
        const int c = idx >> 6, k4 = idx & 63;
        Wt4[k4 * 64 + c] = *reinterpret_cast<const float4*>(W + c * IN_DIM + k4 * 4);
    }
    __syncthreads();

    const int lane = t & 63;
    const float a_s = a[lane];
    const float a_d = a[OUT_DIM + lane];

    const int n_gwaves = gridDim.x * 4;
    const int gwave = blockIdx.x * 4 + (t >> 6);

    for (int base = gwave * 8; base < N_NODES; base += n_gwaves * 8) {
        const int ub = __builtin_amdgcn_readfirstlane(base);
        const float* __restrict__ hrow = h + (size_t)ub * IN_DIM;

        float acc[8];
        #pragma unroll
        for (int n = 0; n < 8; ++n) acc[n] = 0.f;

        for (int k4 = 0; k4 < 64; ++k4) {
            const float4 w = Wt4[k4 * 64 + lane];
            #pragma unroll
            for (int n = 0; n < 8; ++n) {
                acc[n] = fmaf(hrow[n * IN_DIM + k4 * 4 + 0], w.x, acc[n]);
                acc[n] = fmaf(hrow[n * IN_DIM + k4 * 4 + 1], w.y, acc[n]);
                acc[n] = fmaf(hrow[n * IN_DIM + k4 * 4 + 2], w.z, acc[n]);
                acc[n] = fmaf(hrow[n * IN_DIM + k4 * 4 + 3], w.w, acc[n]);
            }
        }

        #pragma unroll
        for (int n = 0; n < 8; ++n) {
            Wh[(size_t)(base + n) * OUT_DIM + lane] = acc[n];
            float ps = acc[n] * a_s;
            float pd = acc[n] * a_d;
            #pragma unroll
            for (int off = 32; off > 0; off >>= 1) {
                ps += __shfl_xor(ps, off);
                pd += __shfl_xor(pd, off);
            }
            if (lane == 0) {
                p_src[base + n] = ps;
                p_dst[base + n] = pd;
            }
        }
    }
}

// ---------------------------------------------------------------------------
// CSR build: histogram -> scan -> scatter
// ---------------------------------------------------------------------------
__global__ __launch_bounds__(256) void gat_hist(const int* __restrict__ dst,
                                                int* __restrict__ cnt)
{
    const int e = blockIdx.x * 256 + threadIdx.x;   // grid covers exactly N_EDGES
    atomicAdd(&cnt[dst[e]], 1);
}

#define SCAN_B 512
#define SCAN_NB ((N_NODES + SCAN_B - 1) / SCAN_B)   // 196

__global__ __launch_bounds__(SCAN_B) void scan_phase1(
    const int* __restrict__ cnt, int* __restrict__ off, int* __restrict__ bsum)
{
    __shared__ int tmp[SCAN_B];
    const int i = blockIdx.x * SCAN_B + threadIdx.x;
    const int v = (i < N_NODES) ? cnt[i] : 0;
    tmp[threadIdx.x] = v;
    __syncthreads();
    int val = v;
    for (int s = 1; s < SCAN_B; s <<= 1) {
        const int add = (threadIdx.x >= s) ? tmp[threadIdx.x - s] : 0;
        __syncthreads();
        val += add;
        tmp[threadIdx.x] = val;
        __syncthreads();
    }
    if (i < N_NODES) off[i] = val - v;               // exclusive within block
    if (threadIdx.x == SCAN_B - 1) bsum[blockIdx.x] = val;
}

__global__ __launch_bounds__(256) void scan_phase2(int* __restrict__ bsum)
{
    __shared__ int tmp[256];
    const int v = (threadIdx.x < SCAN_NB) ? bsum[threadIdx.x] : 0;
    tmp[threadIdx.x] = v;
    __syncthreads();
    int val = v;
    for (int s = 1; s < 256; s <<= 1) {
        const int add = (threadIdx.x >= s) ? tmp[threadIdx.x - s] : 0;
        __syncthreads();
        val += add;
        tmp[threadIdx.x] = val;
        __syncthreads();
    }
    if (threadIdx.x < SCAN_NB) bsum[threadIdx.x] = val - v;  // exclusive
}

__global__ __launch_bounds__(SCAN_B) void scan_phase3(int* __restrict__ off,
                                                      const int* __restrict__ bsum)
{
    const int i = blockIdx.x * SCAN_B + threadIdx.x;
    if (i < N_NODES) off[i] += bsum[blockIdx.x];
    if (i == 0) off[N_NODES] = N_EDGES;
}

__global__ __launch_bounds__(256) void gat_scatter(
    const int* __restrict__ src, const int* __restrict__ dst,
    const float* __restrict__ p_src, const int* __restrict__ off,
    int* __restrict__ cursor, int* __restrict__ csr_src, float* __restrict__ csr_ps)
{
    const int e = blockIdx.x * 256 + threadIdx.x;   // grid covers exactly N_EDGES
    const int de = dst[e];
    const int pos = off[de] + atomicAdd(&cursor[de], 1);
    const int se = src[e];
    csr_src[pos] = se;
    csr_ps[pos] = p_src[se];
}

// ---------------------------------------------------------------------------
// Aggregation: one wave per node. Lane-parallel max/sum over the node's edge
// segment (shuffle reductions), then lane=column register accumulation of
// sum_e ex * Wh[src_e], one coalesced 256B write. No atomics anywhere.
// ---------------------------------------------------------------------------
__global__ __launch_bounds__(256) void gat_aggregate_csr(
    const int* __restrict__ csr_src, const float* __restrict__ csr_ps,
    const int* __restrict__ off, const float* __restrict__ p_dst,
    const float* __restrict__ Wh, float* __restrict__ out)
{
    const int lane = threadIdx.x & 63;
    const int node = __builtin_amdgcn_readfirstlane(blockIdx.x * 4 + (threadIdx.x >> 6));
    const int o = __builtin_amdgcn_readfirstlane(off[node]);
    const int d = __builtin_amdgcn_readfirstlane(off[node + 1]) - o;
    const float pd = p_dst[node];

    // pass A: segment max (lanes stride the segment)
    float mloc = -INFINITY;
    for (int k = lane; k < d; k += 64)
        mloc = fmaxf(mloc, fmaxf(csr_ps[o + k] + pd, 0.f));
    #pragma unroll
    for (int w = 32; w > 0; w >>= 1) mloc = fmaxf(mloc, __shfl_xor(mloc, w));
    const float m = mloc;

    // pass B: segment sum of exp(e - m)
    float ssum = 0.f;
    for (int k = lane; k < d; k += 64)
        ssum += __expf(fmaxf(csr_ps[o + k] + pd, 0.f) - m);
    #pragma unroll
    for (int w = 32; w > 0; w >>= 1) ssum += __shfl_xor(ssum, w);
    const float inv_s = (d > 0) ? (1.f / ssum) : 0.f;

    // pass C: acc[lane] = sum_k exp(e_k - m) * Wh[src_k][lane], unrolled x4
    float acc = 0.f;
    int k = 0;
    for (; k + 4 <= d; k += 4) {
        const int sv0 = csr_src[o + k + 0];
        const int sv1 = csr_src[o + k + 1];
        const int sv2 = csr_src[o + k + 2];
        const int sv3 = csr_src[o + k + 3];
        const float w0 = Wh[(size_t)sv0 * OUT_DIM + lane];
        const float w1 = Wh[(size_t)sv1 * OUT_DIM + lane];
        const float w2 = Wh[(size_t)sv2 * OUT_DIM + lane];
        const float w3 = Wh[(size_t)sv3 * OUT_DIM + lane];
        const float e0 = __expf(fmaxf(csr_ps[o + k + 0] + pd, 0.f) - m);
        const float e1 = __expf(fmaxf(csr_ps[o + k + 1] + pd, 0.f) - m);
        const float e2 = __expf(fmaxf(csr_ps[o + k + 2] + pd, 0.f) - m);
        const float e3 = __expf(fmaxf(csr_ps[o + k + 3] + pd, 0.f) - m);
        acc = fmaf(e0, w0, acc);
        acc = fmaf(e1, w1, acc);
        acc = fmaf(e2, w2, acc);
        acc = fmaf(e3, w3, acc);
    }
    for (; k < d; ++k) {
        const int sv = csr_src[o + k];
        const float ex = __expf(fmaxf(csr_ps[o + k] + pd, 0.f) - m);
        acc = fmaf(ex, Wh[(size_t)sv * OUT_DIM + lane], acc);
    }

    out[(size_t)node * OUT_DIM + lane] = acc * inv_s;
}

// ---------------------------------------------------------------------------
extern "C" void kernel_launch(void* const* d_in, const int* in_sizes, int n_in,
                              void* d_out, int out_size, void* d_ws, size_t ws_size,
                              hipStream_t stream)
{
    const float* h  = (const float*)d_in[0];
    const int* src  = (const int*)d_in[1];
    const int* dst  = (const int*)d_in[2];
    const float* W  = (const float*)d_in[3];
    const float* a  = (const float*)d_in[4];
    float* out = (float*)d_out;

    // workspace layout (bytes)
    char* ws = (char*)d_ws;
    float* Wh     = (float*)(ws);                    // 25,600,000
    float* p_src  = (float*)(ws + 25600000);         //    400,000
    float* p_dst  = (float*)(ws + 26000000);         //    400,000
    int*   cnt    = (int*)  (ws + 26400000);         //    400,000 (reused as cursor)
    int*   off    = (int*)  (ws + 26800000);         //    400,016 (N_NODES+1)
    int*   bsum   = (int*)  (ws + 27200016);         //     16,000
    int*   csr_src= (int*)  (ws + 27216016);         //  6,400,000
    float* csr_ps = (float*)(ws + 33616016);         //  6,400,000  (end ~40.0 MB)

    hipMemsetAsync(cnt, 0, N_NODES * sizeof(int), stream);

    gat_gemm<<<512, 256, 0, stream>>>(h, W, a, Wh, p_src, p_dst);

    const int eb = N_EDGES / 256;                    // 6250, exact
    gat_hist<<<eb, 256, 0, stream>>>(dst, cnt);
    scan_phase1<<<SCAN_NB, SCAN_B, 0, stream>>>(cnt, off, bsum);
    hipMemsetAsync(cnt, 0, N_NODES * sizeof(int), stream);  // cnt -> cursor
    scan_phase2<<<1, 256, 0, stream>>>(bsum);
    scan_phase3<<<SCAN_NB, SCAN_B, 0, stream>>>(off, bsum);
    gat_scatter<<<eb, 256, 0, stream>>>(src, dst, p_src, off, cnt, csr_src, csr_ps);

    gat_aggregate_csr<<<N_NODES / 4, 256, 0, stream>>>(csr_src, csr_ps, off, p_dst, Wh, out);
}

// Round 3
// 299.951 us; speedup vs baseline: 2.1686x; 1.2078x over previous
//
#include <hip/hip_runtime.h>
#include <hip/hip_bf16.h>
#include <math.h>
#include <stdint.h>

#define N_NODES 100000
#define N_EDGES 1600000
#define IN_DIM 256
#define OUT_DIM 64

typedef __attribute__((address_space(1))) const void GV;
typedef __attribute__((address_space(3))) void LV;

// ---------------------------------------------------------------------------
// Kernel A: W_h = h @ W.T  (100000x256 @ 256x64) + p_src/p_dst epilogue.
// Block: 256 thr, tile 64 nodes x 64 cols, K in 8 chunks of 32.
// Thread (ng = t&15, cg = t>>4): nodes ng+16i (i=0..3), cols 4cg+j (j=0..3).
// h/W tiles staged by global_load_lds (16B) into linear LDS with XOR swizzle
// (chunk ^ row&7) pre-applied on the GLOBAL source address; reads re-apply it.
// All data loads are VMEM/LDS — no SMEM on the data path (lgkmcnt decoupled).
// ---------------------------------------------------------------------------
__global__ __launch_bounds__(256, 4) void gat_gemm(
    const float* __restrict__ h, const float* __restrict__ W,
    const float* __restrict__ a, float* __restrict__ Wh,
    float* __restrict__ p_src, float* __restrict__ p_dst)
{
    // LDS: [buf0: h 8K | W 8K][buf1: h 8K | W 8K][p_part 8K]
    __shared__ char smem[40960];

    const int t = threadIdx.x;
    const int lane = t & 63;
    const int wv = t >> 6;          // wave id 0..3
    const int ng = t & 15;
    const int cg = t >> 4;          // 0..15
    const int node0 = blockIdx.x * 64;

    // --- staging addresses (per wave: 2 chunks of 1KB for h, same for W) ---
    // dest byte o = chunk*1024 + lane*16 -> row r = chunk*8 + (lane>>3),
    // slot = lane&7; source k-chunk = slot ^ (r&7)  (XOR swizzle).
    const int chunk0 = wv * 2;
    const int r0 = chunk0 * 8 + (lane >> 3);
    const int r1 = r0 + 8;
    const int ks0 = (lane & 7) ^ (r0 & 7);
    const int ks1 = (lane & 7) ^ (r1 & 7);
    const int hrow0 = (node0 + r0 < N_NODES) ? node0 + r0 : N_NODES - 1;
    const int hrow1 = (node0 + r1 < N_NODES) ? node0 + r1 : N_NODES - 1;

    // --- compute-side LDS offsets ---
    int hbase[4], wbase[4], wxor[4];
    #pragma unroll
    for (int i = 0; i < 4; ++i) hbase[i] = (ng + 16 * i) * 128;
    const int hxor = (ng & 7) << 4;
    #pragma unroll
    for (int j = 0; j < 4; ++j) {
        wbase[j] = (4 * cg + j) * 128;
        wxor[j] = ((4 * cg + j) & 7) << 4;
    }

    float acc[4][4];
    #pragma unroll
    for (int i = 0; i < 4; ++i)
        #pragma unroll
        for (int j = 0; j < 4; ++j) acc[i][j] = 0.f;

    // --- stage one k-tile (kc = float offset) into buffer b ---
    #define STAGE(b, kc)                                                        \
    {                                                                           \
        char* hb = smem + (b) * 16384;                                          \
        char* wb = hb + 8192;                                                   \
        __builtin_amdgcn_global_load_lds(                                       \
            (GV*)(h + (size_t)hrow0 * IN_DIM + (kc) + ks0 * 4),                 \
            (LV*)(hb + chunk0 * 1024), 16, 0, 0);                               \
        __builtin_amdgcn_global_load_lds(                                       \
            (GV*)(h + (size_t)hrow1 * IN_DIM + (kc) + ks1 * 4),                 \
            (LV*)(hb + chunk0 * 1024 + 1024), 16, 0, 0);                        \
        __builtin_amdgcn_global_load_lds(                                       \
            (GV*)(W + (size_t)r0 * IN_DIM + (kc) + ks0 * 4),                    \
            (LV*)(wb + chunk0 * 1024), 16, 0, 0);                               \
        __builtin_amdgcn_global_load_lds(                                       \
            (GV*)(W + (size_t)r1 * IN_DIM + (kc) + ks1 * 4),                    \
            (LV*)(wb + chunk0 * 1024 + 1024), 16, 0, 0);                        \
    }

    STAGE(0, 0);
    asm volatile("s_waitcnt vmcnt(0)");
    __syncthreads();

    int cur = 0;
    #pragma unroll
    for (int kt = 0; kt < 8; ++kt) {
        if (kt < 7) STAGE(cur ^ 1, (kt + 1) * 32);

        const char* hb = smem + cur * 16384;
        const char* wb = hb + 8192;
        #pragma unroll
        for (int kk4 = 0; kk4 < 8; ++kk4) {
            float4 hv[4], wvv[4];
            #pragma unroll
            for (int i = 0; i < 4; ++i)
                hv[i] = *(const float4*)(hb + hbase[i] + (((kk4 << 4) ^ hxor)));
            #pragma unroll
            for (int j = 0; j < 4; ++j)
                wvv[j] = *(const float4*)(wb + wbase[j] + (((kk4 << 4) ^ wxor[j])));
            #pragma unroll
            for (int i = 0; i < 4; ++i)
                #pragma unroll
                for (int j = 0; j < 4; ++j) {
                    acc[i][j] = fmaf(hv[i].x, wvv[j].x, acc[i][j]);
                    acc[i][j] = fmaf(hv[i].y, wvv[j].y, acc[i][j]);
                    acc[i][j] = fmaf(hv[i].z, wvv[j].z, acc[i][j]);
                    acc[i][j] = fmaf(hv[i].w, wvv[j].w, acc[i][j]);
                }
        }

        if (kt < 7) asm volatile("s_waitcnt vmcnt(0)");
        __syncthreads();
        cur ^= 1;
    }
    #undef STAGE

    // --- store Wh (float4 per node) ---
    #pragma unroll
    for (int i = 0; i < 4; ++i) {
        const int n = node0 + ng + 16 * i;
        if (n < N_NODES) {
            float4 v = make_float4(acc[i][0], acc[i][1], acc[i][2], acc[i][3]);
            *(float4*)(Wh + (size_t)n * OUT_DIM + 4 * cg) = v;
        }
    }

    // --- fused p_src/p_dst: partial dot with a, LDS reduce over cg ---
    const float4 as = *(const float4*)(a + 4 * cg);
    const float4 ad = *(const float4*)(a + OUT_DIM + 4 * cg);
    float* pp = (float*)(smem + 32768);   // [2][16][64]
    #pragma unroll
    for (int i = 0; i < 4; ++i) {
        const int nl = ng + 16 * i;
        pp[cg * 64 + nl] =
            acc[i][0] * as.x + acc[i][1] * as.y + acc[i][2] * as.z + acc[i][3] * as.w;
        pp[1024 + cg * 64 + nl] =
            acc[i][0] * ad.x + acc[i][1] * ad.y + acc[i][2] * ad.z + acc[i][3] * ad.w;
    }
    __syncthreads();
    if (t < 128) {
        const int which = t >> 6, nl = t & 63;
        float s = 0.f;
        #pragma unroll
        for (int c = 0; c < 16; ++c) s += pp[which * 1024 + c * 64 + nl];
        if (node0 + nl < N_NODES) {
            if (which) p_dst[node0 + nl] = s;
            else       p_src[node0 + nl] = s;
        }
    }
}

// ---------------------------------------------------------------------------
// CSR build: histogram -> scan -> scatter
// ---------------------------------------------------------------------------
__global__ __launch_bounds__(256) void gat_hist(const int* __restrict__ dst,
                                                int* __restrict__ cnt)
{
    const int e = blockIdx.x * 256 + threadIdx.x;
    atomicAdd(&cnt[dst[e]], 1);
}

#define SCAN_B 512
#define SCAN_NB ((N_NODES + SCAN_B - 1) / SCAN_B)   // 196

__global__ __launch_bounds__(SCAN_B) void scan_phase1(
    const int* __restrict__ cnt, int* __restrict__ off, int* __restrict__ bsum)
{
    __shared__ int tmp[SCAN_B];
    const int i = blockIdx.x * SCAN_B + threadIdx.x;
    const int v = (i < N_NODES) ? cnt[i] : 0;
    tmp[threadIdx.x] = v;
    __syncthreads();
    int val = v;
    for (int s = 1; s < SCAN_B; s <<= 1) {
        const int add = (threadIdx.x >= s) ? tmp[threadIdx.x - s] : 0;
        __syncthreads();
        val += add;
        tmp[threadIdx.x] = val;
        __syncthreads();
    }
    if (i < N_NODES) off[i] = val - v;
    if (threadIdx.x == SCAN_B - 1) bsum[blockIdx.x] = val;
}

__global__ __launch_bounds__(256) void scan_phase2(int* __restrict__ bsum)
{
    __shared__ int tmp[256];
    const int v = (threadIdx.x < SCAN_NB) ? bsum[threadIdx.x] : 0;
    tmp[threadIdx.x] = v;
    __syncthreads();
    int val = v;
    for (int s = 1; s < 256; s <<= 1) {
        const int add = (threadIdx.x >= s) ? tmp[threadIdx.x - s] : 0;
        __syncthreads();
        val += add;
        tmp[threadIdx.x] = val;
        __syncthreads();
    }
    if (threadIdx.x < SCAN_NB) bsum[threadIdx.x] = val - v;
}

__global__ __launch_bounds__(SCAN_B) void scan_phase3(int* __restrict__ off,
                                                      const int* __restrict__ bsum)
{
    const int i = blockIdx.x * SCAN_B + threadIdx.x;
    if (i < N_NODES) off[i] += bsum[blockIdx.x];
    if (i == 0) off[N_NODES] = N_EDGES;
}

__global__ __launch_bounds__(256) void gat_scatter(
    const int* __restrict__ src, const int* __restrict__ dst,
    const float* __restrict__ p_src, const int* __restrict__ off,
    int* __restrict__ cursor, int* __restrict__ csr_src, float* __restrict__ csr_ps)
{
    const int e = blockIdx.x * 256 + threadIdx.x;
    const int de = dst[e];
    const int pos = off[de] + atomicAdd(&cursor[de], 1);
    const int se = src[e];
    csr_src[pos] = se;
    csr_ps[pos] = p_src[se];
}

// ---------------------------------------------------------------------------
// Aggregation: one wave per node, lane = column; no atomics.
// ---------------------------------------------------------------------------
__global__ __launch_bounds__(256) void gat_aggregate_csr(
    const int* __restrict__ csr_src, const float* __restrict__ csr_ps,
    const int* __restrict__ off, const float* __restrict__ p_dst,
    const float* __restrict__ Wh, float* __restrict__ out)
{
    const int lane = threadIdx.x & 63;
    const int node = __builtin_amdgcn_readfirstlane(blockIdx.x * 4 + (threadIdx.x >> 6));
    const int o = __builtin_amdgcn_readfirstlane(off[node]);
    const int d = __builtin_amdgcn_readfirstlane(off[node + 1]) - o;
    const float pd = p_dst[node];

    float mloc = -INFINITY;
    for (int k = lane; k < d; k += 64)
        mloc = fmaxf(mloc, fmaxf(csr_ps[o + k] + pd, 0.f));
    #pragma unroll
    for (int w = 32; w > 0; w >>= 1) mloc = fmaxf(mloc, __shfl_xor(mloc, w));
    const float m = mloc;

    float ssum = 0.f;
    for (int k = lane; k < d; k += 64)
        ssum += __expf(fmaxf(csr_ps[o + k] + pd, 0.f) - m);
    #pragma unroll
    for (int w = 32; w > 0; w >>= 1) ssum += __shfl_xor(ssum, w);
    const float inv_s = (d > 0) ? (1.f / ssum) : 0.f;

    float acc = 0.f;
    int k = 0;
    for (; k + 4 <= d; k += 4) {
        const int sv0 = csr_src[o + k + 0];
        const int sv1 = csr_src[o + k + 1];
        const int sv2 = csr_src[o + k + 2];
        const int sv3 = csr_src[o + k + 3];
        const float w0 = Wh[(size_t)sv0 * OUT_DIM + lane];
        const float w1 = Wh[(size_t)sv1 * OUT_DIM + lane];
        const float w2 = Wh[(size_t)sv2 * OUT_DIM + lane];
        const float w3 = Wh[(size_t)sv3 * OUT_DIM + lane];
        const float e0 = __expf(fmaxf(csr_ps[o + k + 0] + pd, 0.f) - m);
        const float e1 = __expf(fmaxf(csr_ps[o + k + 1] + pd, 0.f) - m);
        const float e2 = __expf(fmaxf(csr_ps[o + k + 2] + pd, 0.f) - m);
        const float e3 = __expf(fmaxf(csr_ps[o + k + 3] + pd, 0.f) - m);
        acc = fmaf(e0, w0, acc);
        acc = fmaf(e1, w1, acc);
        acc = fmaf(e2, w2, acc);
        acc = fmaf(e3, w3, acc);
    }
    for (; k < d; ++k) {
        const int sv = csr_src[o + k];
        const float ex = __expf(fmaxf(csr_ps[o + k] + pd, 0.f) - m);
        acc = fmaf(ex, Wh[(size_t)sv * OUT_DIM + lane], acc);
    }

    out[(size_t)node * OUT_DIM + lane] = acc * inv_s;
}

// ---------------------------------------------------------------------------
extern "C" void kernel_launch(void* const* d_in, const int* in_sizes, int n_in,
                              void* d_out, int out_size, void* d_ws, size_t ws_size,
                              hipStream_t stream)
{
    const float* h  = (const float*)d_in[0];
    const int* src  = (const int*)d_in[1];
    const int* dst  = (const int*)d_in[2];
    const float* W  = (const float*)d_in[3];
    const float* a  = (const float*)d_in[4];
    float* out = (float*)d_out;

    char* ws = (char*)d_ws;
    float* Wh     = (float*)(ws);                    // 25,600,000
    float* p_src  = (float*)(ws + 25600000);         //    400,000
    float* p_dst  = (float*)(ws + 26000000);         //    400,000
    int*   cnt    = (int*)  (ws + 26400000);         //    400,000 (reused as cursor)
    int*   off    = (int*)  (ws + 26800000);         //    400,016 (N_NODES+1)
    int*   bsum   = (int*)  (ws + 27200016);         //     16,000
    int*   csr_src= (int*)  (ws + 27216016);         //  6,400,000
    float* csr_ps = (float*)(ws + 33616016);         //  6,400,000

    hipMemsetAsync(cnt, 0, N_NODES * sizeof(int), stream);

    gat_gemm<<<(N_NODES + 63) / 64, 256, 0, stream>>>(h, W, a, Wh, p_src, p_dst);

    const int eb = N_EDGES / 256;                    // 6250, exact
    gat_hist<<<eb, 256, 0, stream>>>(dst, cnt);
    scan_phase1<<<SCAN_NB, SCAN_B, 0, stream>>>(cnt, off, bsum);
    hipMemsetAsync(cnt, 0, N_NODES * sizeof(int), stream);  // cnt -> cursor
    scan_phase2<<<1, 256, 0, stream>>>(bsum);
    scan_phase3<<<SCAN_NB, SCAN_B, 0, stream>>>(off, bsum);
    gat_scatter<<<eb, 256, 0, stream>>>(src, dst, p_src, off, cnt, csr_src, csr_ps);

    gat_aggregate_csr<<<N_NODES / 4, 256, 0, stream>>>(csr_src, csr_ps, off, p_dst, Wh, out);
}